// Round 6
// baseline (14206.729 us; speedup 1.0000x reference)
//
#include <hip/hip_runtime.h>
#include <stdint.h>

// DecoderRNN R21: R20 protocol (flag vectors, per-wave detect, fadd y-acc)
// with the R20 BUG fixed: yacc read was destructive (read+rezero) with 32
// independent role0 readers -> fast WG's zero beat slow WG's read (absmax
// 0.49 = one y value). Fix: 4-slot rotating accumulator yacc[4][64]:
//  role3 step t: fadd into slot t&3, ZERO slot (t+2)&3 (time-disjoint from
//  all fadds/reads of that slot via the existing h0->h1->y flag chain);
//  role0 step t: non-destructive read of slot (t-1)&3.
// Also: role2's gh1 single-slot poll loads from lane 0 only (same-address
// multi-lane atomic loads serialize at LLC).
// Everything else identical to R20/R19 (planar hi/lo h, hi-only critical
// hops, sc0sc1 coalesced data path, producer drain -> flag discipline).

#define NWG 128
#define NT  256
#define TT  1024

typedef unsigned short ushort;
typedef unsigned int   uint;
typedef __attribute__((ext_vector_type(8))) short short8;
typedef __attribute__((ext_vector_type(4))) float f32x4;
typedef __attribute__((ext_vector_type(4))) uint  uint4v;

struct __align__(16) Smem {
  ushort wpl[2][48*520];
  float  gictx[3*16*68];
  float  wcol[3][16];
  float  bsumR[16], bsumZ[16], binN[16], bhnN[16];
  float  bo1v[16], wo2v[16];
  float  prevS[64];
};

__device__ __forceinline__ float frcp(float x){
#if __has_builtin(__builtin_amdgcn_rcpf)
  return __builtin_amdgcn_rcpf(x);
#else
  return 1.f/x;
#endif
}
__device__ __forceinline__ float sigm(float x){ return frcp(1.f + __expf(-x)); }
__device__ __forceinline__ float tanh_f(float x){
  return 1.f - 2.f*frcp(__expf(2.f*x) + 1.f);
}
__device__ __forceinline__ float bf2f(ushort h){ return __uint_as_float(((uint)h)<<16); }
__device__ __forceinline__ ushort bfrnd(float x){
  uint u = __float_as_uint(x);
  return (ushort)((u + 0x7fffu + ((u>>16)&1u)) >> 16);
}
#define SWP(p, v)   (void)__hip_atomic_exchange((uint*)(p), (uint)(v), __ATOMIC_RELAXED, __HIP_MEMORY_SCOPE_AGENT)
#define ALD1(p)     __hip_atomic_load((const uint*)(p), __ATOMIC_RELAXED, __HIP_MEMORY_SCOPE_AGENT)
#define ALDF(p)     __uint_as_float(ALD1(p))
#define ASTORE(p,v) __hip_atomic_store((int*)(p), (v), __ATOMIC_RELAXED, __HIP_MEMORY_SCOPE_AGENT)
#define FADDF(p,v)  (void)__hip_atomic_fetch_add((float*)(p), (v), __ATOMIC_RELAXED, __HIP_MEMORY_SCOPE_AGENT)

// init/final global barrier (epoch-monotonic)
__device__ __forceinline__ void gbar(int* slots, int* epoch, int w, int tid, int e){
  __syncthreads();
  if (tid == 0)
    __hip_atomic_store(&slots[w], e, __ATOMIC_RELEASE, __HIP_MEMORY_SCOPE_AGENT);
  if (w == 0 && tid < 64){
    for(;;){
      int m0 = __hip_atomic_load(&slots[tid*2+0], __ATOMIC_RELAXED, __HIP_MEMORY_SCOPE_AGENT);
      int m1 = __hip_atomic_load(&slots[tid*2+1], __ATOMIC_RELAXED, __HIP_MEMORY_SCOPE_AGENT);
      if (__all(min(m0,m1) >= e)) break;
      __builtin_amdgcn_s_sleep(1);
    }
    if (tid == 0){
      __builtin_amdgcn_fence(__ATOMIC_ACQUIRE, "agent");
      __hip_atomic_store(epoch, e, __ATOMIC_RELEASE, __HIP_MEMORY_SCOPE_AGENT);
    }
  }
  if (tid == 0){
    while (__hip_atomic_load(epoch, __ATOMIC_RELAXED, __HIP_MEMORY_SCOPE_AGENT) < e)
      __builtin_amdgcn_s_sleep(1);
    __builtin_amdgcn_fence(__ATOMIC_ACQUIRE, "agent");
  }
  __syncthreads();
}

__device__ __forceinline__ void drain_sync(){
  __builtin_amdgcn_s_waitcnt(0);
  __syncthreads();
}
// per-wave 32-producer flag-vector poll: lanes 0..31 each watch one slot
__device__ __forceinline__ void waitvec(const int* line, int target, int lane){
  for(;;){
    int vv = (lane < 32) ? (int)ALD1(line + lane) : target;
    if (__all(vv >= target)) break;
  }
}
// per-wave single-slot poll: lane 0 loads, wave exits together
__device__ __forceinline__ void waitone(const int* p, int target, int lane){
  for(;;){
    int vv = (lane == 0) ? (int)ALD1(p) : target;
    if (__all(vv >= target)) break;
  }
}

// coherent LLC-direct ops (sc0 sc1 = bypass L1+L2, coalesced)
#define LD1SC(dst, addr) \
  asm volatile("global_load_dwordx4 %0, %1, off sc0 sc1" : "=v"(dst) : "v"(addr));
#define LD1SCD(dst, addr) \
  asm volatile("global_load_dword %0, %1, off sc0 sc1" : "=v"(dst) : "v"(addr));
#define STSH(addr, val) \
  asm volatile("global_store_short %0, %1, off sc0 sc1" :: "v"(addr), "v"(val) : "memory");
#define ST1SCW(addr, val) \
  asm volatile("global_store_dword %0, %1, off sc0 sc1" :: "v"(addr), "v"(val) : "memory");
#define ST4SC(addr, val) \
  asm volatile("global_store_dwordx4 %0, %1, off sc0 sc1" :: "v"(addr), "v"(val) : "memory");
#define WB1(a)     asm volatile("s_waitcnt vmcnt(0)" : "+v"(a));
#define WB3(a,b,c) asm volatile("s_waitcnt vmcnt(0)" : "+v"(a),"+v"(b),"+v"(c));
#define VMBAR8(a,b,c,d,e,f,g,h) \
  asm volatile("s_waitcnt vmcnt(0)" \
               : "+v"(a),"+v"(b),"+v"(c),"+v"(d),"+v"(e),"+v"(f),"+v"(g),"+v"(h));

// planar A-frag loads: plane P (ushort*), lane row 16v+col, k = i*32+q*8
#define LDH(P, i) \
  asm volatile("global_load_dwordx4 %0, %1, off sc0 sc1" \
               : "=v"(ha##i) : "v"((P) + aoffB + (i)*32));
#define LDL(P, i) \
  asm volatile("global_load_dwordx4 %0, %1, off sc0 sc1" \
               : "=v"(la##i) : "v"((P) + aoffB + (i)*32));

#define DECL_HI(P) \
  uint4v ha0,ha1,ha2,ha3,ha4,ha5,ha6,ha7,ha8,ha9,ha10,ha11,ha12,ha13,ha14,ha15; \
  LDH(P,0) LDH(P,1) LDH(P,2) LDH(P,3) LDH(P,4) LDH(P,5) LDH(P,6) LDH(P,7) \
  LDH(P,8) LDH(P,9) LDH(P,10) LDH(P,11) LDH(P,12) LDH(P,13) LDH(P,14) LDH(P,15) \
  VMBAR8(ha0,ha1,ha2,ha3,ha4,ha5,ha6,ha7) \
  VMBAR8(ha8,ha9,ha10,ha11,ha12,ha13,ha14,ha15)

#define DECL_HILO(PH, PL) \
  uint4v ha0,ha1,ha2,ha3,ha4,ha5,ha6,ha7,ha8,ha9,ha10,ha11,ha12,ha13,ha14,ha15; \
  uint4v la0,la1,la2,la3,la4,la5,la6,la7,la8,la9,la10,la11,la12,la13,la14,la15; \
  LDH(PH,0) LDH(PH,1) LDH(PH,2) LDH(PH,3) LDH(PH,4) LDH(PH,5) LDH(PH,6) LDH(PH,7) \
  LDH(PH,8) LDH(PH,9) LDH(PH,10) LDH(PH,11) LDH(PH,12) LDH(PH,13) LDH(PH,14) LDH(PH,15) \
  LDL(PL,0) LDL(PL,1) LDL(PL,2) LDL(PL,3) LDL(PL,4) LDL(PL,5) LDL(PL,6) LDL(PL,7) \
  LDL(PL,8) LDL(PL,9) LDL(PL,10) LDL(PL,11) LDL(PL,12) LDL(PL,13) LDL(PL,14) LDL(PL,15) \
  VMBAR8(ha0,ha1,ha2,ha3,ha4,ha5,ha6,ha7) \
  VMBAR8(ha8,ha9,ha10,ha11,ha12,ha13,ha14,ha15) \
  VMBAR8(la0,la1,la2,la3,la4,la5,la6,la7) \
  VMBAR8(la8,la9,la10,la11,la12,la13,la14,la15)

#define MFMA_ __builtin_amdgcn_mfma_f32_16x16x32_bf16

// full precision (roles 0/1): 9 MFMAs per i
#define MS3F(i) { \
  short8 AH_ = __builtin_bit_cast(short8, ha##i); \
  short8 AL_ = __builtin_bit_cast(short8, la##i); \
  const int ko_ = (i)*32 + q*8; \
  short8 bh_ = *(const short8*)(&S.wpl[0][(col)*520 + ko_]); \
  short8 bl_ = *(const short8*)(&S.wpl[1][(col)*520 + ko_]); \
  acc0 = MFMA_(AH_, bh_, acc0, 0,0,0); \
  acc0 = MFMA_(AL_, bh_, acc0, 0,0,0); \
  acc0 = MFMA_(AH_, bl_, acc0, 0,0,0); \
  bh_ = *(const short8*)(&S.wpl[0][(16+col)*520 + ko_]); \
  bl_ = *(const short8*)(&S.wpl[1][(16+col)*520 + ko_]); \
  acc1 = MFMA_(AH_, bh_, acc1, 0,0,0); \
  acc1 = MFMA_(AL_, bh_, acc1, 0,0,0); \
  acc1 = MFMA_(AH_, bl_, acc1, 0,0,0); \
  bh_ = *(const short8*)(&S.wpl[0][(32+col)*520 + ko_]); \
  bl_ = *(const short8*)(&S.wpl[1][(32+col)*520 + ko_]); \
  acc2 = MFMA_(AH_, bh_, acc2, 0,0,0); \
  acc2 = MFMA_(AL_, bh_, acc2, 0,0,0); \
  acc2 = MFMA_(AH_, bl_, acc2, 0,0,0); }

// hi-only A (role 2): 6 MFMAs per i
#define MS3H(i) { \
  short8 AH_ = __builtin_bit_cast(short8, ha##i); \
  const int ko_ = (i)*32 + q*8; \
  short8 bh_ = *(const short8*)(&S.wpl[0][(col)*520 + ko_]); \
  short8 bl_ = *(const short8*)(&S.wpl[1][(col)*520 + ko_]); \
  acc0 = MFMA_(AH_, bh_, acc0, 0,0,0); \
  acc0 = MFMA_(AH_, bl_, acc0, 0,0,0); \
  bh_ = *(const short8*)(&S.wpl[0][(16+col)*520 + ko_]); \
  bl_ = *(const short8*)(&S.wpl[1][(16+col)*520 + ko_]); \
  acc1 = MFMA_(AH_, bh_, acc1, 0,0,0); \
  acc1 = MFMA_(AH_, bl_, acc1, 0,0,0); \
  bh_ = *(const short8*)(&S.wpl[0][(32+col)*520 + ko_]); \
  bl_ = *(const short8*)(&S.wpl[1][(32+col)*520 + ko_]); \
  acc2 = MFMA_(AH_, bh_, acc2, 0,0,0); \
  acc2 = MFMA_(AH_, bl_, acc2, 0,0,0); }

// hi-only A, single output block (role 3): 2 MFMAs per i
#define MS1H(i) { \
  short8 AH_ = __builtin_bit_cast(short8, ha##i); \
  const int ko_ = (i)*32 + q*8; \
  short8 bh_ = *(const short8*)(&S.wpl[0][(col)*520 + ko_]); \
  short8 bl_ = *(const short8*)(&S.wpl[1][(col)*520 + ko_]); \
  acc0 = MFMA_(AH_, bh_, acc0, 0,0,0); \
  acc0 = MFMA_(AH_, bl_, acc0, 0,0,0); }

#define RUN16(M) M(0) M(1) M(2) M(3) M(4) M(5) M(6) M(7) \
                 M(8) M(9) M(10) M(11) M(12) M(13) M(14) M(15)

extern "C" __global__ void __launch_bounds__(NT, 1)
decoder_rnn(const float* __restrict__ ctx,   // [64][512]
            const float* __restrict__ Wih0,  // [1536][513] (row stride 513!)
            const float* __restrict__ Whh0,
            const float* __restrict__ bih0,
            const float* __restrict__ bhh0g,
            const float* __restrict__ Wih1,
            const float* __restrict__ Whh1,
            const float* __restrict__ bih1g,
            const float* __restrict__ bhh1g,
            const float* __restrict__ Wo1,
            const float* __restrict__ bo1g,
            const float* __restrict__ Wo2,
            const float* __restrict__ bo2g,
            float* __restrict__ out,         // [64*1024 y][65536 h_i]
            float* __restrict__ ws)
{
  extern __shared__ char smem_raw[];
  Smem& S = *reinterpret_cast<Smem*>(smem_raw);
  const int tid = threadIdx.x;
  const int wg  = blockIdx.x;

  ushort* hp    = (ushort*)ws;               // planes: h0hi[2]@0/32768,
                                             // h0lo[2]@65536/98304,
                                             // h1hi@131072, h1lo@163840
  float* gh1raw = (float*)ws + 98304;        // 32*3072
  float* yacc   = (float*)ws + 196608;       // [4][64] rotating fadd slots
  int*   ibase  = (int*)((float*)ws + 200704);
  int*   gslots = ibase;                     // [128] gbar
  int*   epoch  = ibase + 128;
  int*   mbox   = ibase + 256;               // [128 consumers][2 flags][32]

  const float bo2v = bo2g[0];

  // ---------------- init (swaps -> LLC; once, off critical path) ----------
  for (int i = wg*NT + tid; i < 200704; i += NWG*NT)
    SWP((uint*)ws + i, 0u);
  if (wg == 0)
    for (int i = tid; i < 128*64; i += NT) SWP(mbox + i, 0);

  const int role = wg >> 5;
  const int j    = wg & 31;
  if (role != 3){
    const float* Wsrc = (role == 0) ? Whh0 : (role == 1) ? Whh1 : Wih1;
    for (int i = tid; i < 48*512; i += NT){
      int r = i >> 9, k = i & 511;
      int g = r >> 4, n = r & 15;
      float wv = Wsrc[(size_t)(g*512 + 16*j + n)*512 + k];
      ushort hh = bfrnd(wv);
      S.wpl[0][r*520 + k] = hh;
      S.wpl[1][r*520 + k] = bfrnd(wv - bf2f(hh));
    }
  } else {
    for (int i = tid; i < 16*512; i += NT){
      int r = i >> 9, k = i & 511;
      float wv = Wo1[(size_t)(16*j + r)*512 + k];
      ushort hh = bfrnd(wv);
      S.wpl[0][r*520 + k] = hh;
      S.wpl[1][r*520 + k] = bfrnd(wv - bf2f(hh));
    }
    if (tid < 16){ S.bo1v[tid] = bo1g[16*j + tid]; S.wo2v[tid] = Wo2[16*j + tid]; }
  }
  if (role == 0){
    if (tid < 48){
      int g = tid >> 4, n = tid & 15;
      S.wcol[g][n] = Wih0[(size_t)(g*512 + 16*j + n)*513 + 512];
    }
    if (tid < 16) S.bhnN[tid] = bhh0g[2*512 + 16*j + tid];
    for (int idx = tid; idx < 3072; idx += NT){
      int r = idx >> 6, b = idx & 63;
      int g = r >> 4, n = r & 15;
      int grow = g*512 + 16*j + n;
      const float* wr = Wih0 + (size_t)grow*513;
      const float* cx = ctx  + (size_t)b*512;
      float s = bih0[grow];
      if (g < 2) s += bhh0g[grow];
      #pragma unroll 4
      for (int k = 0; k < 512; ++k) s += wr[k]*cx[k];
      S.gictx[g*1088 + n*68 + b] = s;
    }
  }
  if (role == 2 && tid < 16){
    int n = tid;
    S.bsumR[n] = bih1g[16*j + n]       + bhh1g[16*j + n];
    S.bsumZ[n] = bih1g[512 + 16*j + n] + bhh1g[512 + 16*j + n];
    S.binN[n]  = bih1g[1024 + 16*j + n];
    S.bhnN[n]  = bhh1g[1024 + 16*j + n];
  }

  gbar(gslots, epoch, wg, tid, 1);

  const int v   = tid >> 6;
  const int l   = tid & 63;
  const int q   = l >> 4;
  const int col = l & 15;
  const int aoffB = (16*v + col)*512 + q*8;   // ushort units within a plane
  const int b0w  = 16*v + 4*q;
  const int ng   = 16*j + col;

  int* lineH = mbox + (wg*2 + 0)*32;          // this WG's data-input flags
  int* lineY = mbox + (wg*2 + 1)*32;          // secondary flags (y / gh1)

  if (role == 0){
    float hc0 = 0.f, hc1 = 0.f, hc2 = 0.f, hc3 = 0.f;   // carried h0-old (fp32)
    for (int t = 0; t < TT; ++t){
      const int r0 = t & 1, w0 = r0 ^ 1;
      waitvec(lineH, t, l);                  // h0[t-1] complete (per-wave)
      const ushort* rH = hp + r0*32768;
      const ushort* rL = hp + 65536 + r0*32768;
      ushort*       wH = hp + w0*32768;
      ushort*       wL = hp + 65536 + w0*32768;
      f32x4 acc0={0,0,0,0}, acc1={0,0,0,0}, acc2={0,0,0,0};
      DECL_HILO(rH, rL)
      RUN16(MS3F)
      waitvec(lineY, t, l);                  // y[t-1] fully accumulated
      if (tid < 64){
        float s = 0.f;
        if (t > 0){
          const float* yp = yacc + ((t-1)&3)*64 + tid;
          float vv;
          LD1SCD(vv, yp)                     // NON-destructive read (no rezero)
          WB1(vv)
          s = vv;
        }
        float pv = fmaxf(s + bo2v, 0.f);
        S.prevS[tid] = pv;
        if (wg == 0 && t > 0) out[(size_t)tid*TT + (t-1)] = pv;
      }
      __syncthreads();
      f32x4 pv4 = *(const f32x4*)&S.prevS[b0w];
      f32x4 gR = *(const f32x4*)&S.gictx[0*1088 + col*68 + b0w];
      f32x4 gZ = *(const f32x4*)&S.gictx[1*1088 + col*68 + b0w];
      f32x4 gN = *(const f32x4*)&S.gictx[2*1088 + col*68 + b0w];
      float wc0 = S.wcol[0][col], wc1 = S.wcol[1][col], wc2 = S.wcol[2][col];
      float bhn = S.bhnN[col];
      #define E0(i, HC) { \
        float rr = sigm(gR[i] + pv4[i]*wc0 + acc0[i]); \
        float zz = sigm(gZ[i] + pv4[i]*wc1 + acc1[i]); \
        float nn = tanh_f(gN[i] + pv4[i]*wc2 + rr*(acc2[i] + bhn)); \
        float h = (1.f-zz)*nn + zz*HC; \
        HC = h; \
        ushort hh_ = bfrnd(h); \
        uint hu_ = hh_, lu_ = bfrnd(h - bf2f(hh_)); \
        STSH(wH + (size_t)(b0w+(i))*512 + ng, hu_) \
        STSH(wL + (size_t)(b0w+(i))*512 + ng, lu_) }
      E0(0,hc0) E0(1,hc1) E0(2,hc2) E0(3,hc3)
      #undef E0
      drain_sync();
      if (tid < 64){                         // h0 flag -> role0 + role2 lines
        int cline = (tid < 32) ? tid : (64 + (tid - 32));
        ASTORE(mbox + (cline*2 + 0)*32 + j, t + 1);
      }
    }
  } else if (role == 1){
    const ushort* rH = hp + 131072;          // h1 hi plane
    const ushort* rL = hp + 163840;          // h1 lo plane
    for (int t = 0; t < TT; ++t){
      waitvec(lineH, t, l);                  // h1[t-1] complete
      f32x4 acc0={0,0,0,0}, acc1={0,0,0,0}, acc2={0,0,0,0};
      DECL_HILO(rH, rL)
      RUN16(MS3F)
      float* gp = gh1raw + (size_t)j*3072 + v*256 + l*4;
      ST4SC(gp,        acc0)
      ST4SC(gp + 1024, acc1)
      ST4SC(gp + 2048, acc2)
      drain_sync();
      if (tid == 0)                          // point-to-point gh1 flag
        ASTORE(mbox + ((64 + j)*2 + 1)*32 + j, t + 1);
    }
  } else if (role == 2){
    ushort* p1H = hp + 131072;
    ushort* p1L = hp + 163840;
    float hc0 = 0.f, hc1 = 0.f, hc2 = 0.f, hc3 = 0.f;   // carried h1-old (fp32)
    for (int t = 0; t < TT; ++t){
      const int w0 = (t & 1) ^ 1;
      waitvec(lineH, t + 1, l);              // h0[t] complete
      waitone(lineY + j, t + 1, l);          // gh1[t] ready (slack: ~always)
      const ushort* rH = hp + w0*32768;      // h0[t] hi plane ONLY (critical)
      const float* gp = gh1raw + (size_t)j*3072 + v*256 + l*4;
      uint4v hRv, hZv, hNv;
      LD1SC(hRv, (const uint*)(gp + 0))
      LD1SC(hZv, (const uint*)(gp + 1024))
      LD1SC(hNv, (const uint*)(gp + 2048))
      f32x4 acc0={0,0,0,0}, acc1={0,0,0,0}, acc2={0,0,0,0};
      DECL_HI(rH)
      WB3(hRv, hZv, hNv)
      RUN16(MS3H)
      f32x4 hR = __builtin_bit_cast(f32x4, hRv);
      f32x4 hZ = __builtin_bit_cast(f32x4, hZv);
      f32x4 hN = __builtin_bit_cast(f32x4, hNv);
      float bsR = S.bsumR[col], bsZ = S.bsumZ[col], biN = S.binN[col], bhN = S.bhnN[col];
      #define E1(i, HC) { \
        float r1 = sigm(acc0[i] + hR[i] + bsR); \
        float z1 = sigm(acc1[i] + hZ[i] + bsZ); \
        float n1 = tanh_f(acc2[i] + biN + r1*(hN[i] + bhN)); \
        float h = (1.f-z1)*n1 + z1*HC; \
        HC = h; \
        ushort hh_ = bfrnd(h); \
        uint hu_ = hh_, lu_ = bfrnd(h - bf2f(hh_)); \
        STSH(p1H + (size_t)(b0w+(i))*512 + ng, hu_) \
        STSH(p1L + (size_t)(b0w+(i))*512 + ng, lu_) }
      E1(0,hc0) E1(1,hc1) E1(2,hc2) E1(3,hc3)
      #undef E1
      drain_sync();
      if (tid < 64){                         // h1 flag -> role1 + role3 lines
        int cline = (tid < 32) ? (32 + tid) : (96 + (tid - 32));
        ASTORE(mbox + (cline*2 + 0)*32 + j, t + 1);
      }
    }
  } else {
    const ushort* rH = hp + 131072;          // h1 hi plane ONLY (critical)
    for (int t = 0; t < TT; ++t){
      waitvec(lineH, t + 1, l);              // h1[t] complete
      f32x4 acc0={0,0,0,0};
      DECL_HI(rH)
      RUN16(MS1H)
      float s0 = S.wo2v[col]*fmaxf(acc0[0] + S.bo1v[col], 0.f);
      float s1 = S.wo2v[col]*fmaxf(acc0[1] + S.bo1v[col], 0.f);
      float s2 = S.wo2v[col]*fmaxf(acc0[2] + S.bo1v[col], 0.f);
      float s3 = S.wo2v[col]*fmaxf(acc0[3] + S.bo1v[col], 0.f);
      #pragma unroll
      for (int d = 1; d < 16; d <<= 1){
        s0 += __shfl_xor(s0, d);
        s1 += __shfl_xor(s1, d);
        s2 += __shfl_xor(s2, d);
        s3 += __shfl_xor(s3, d);
      }
      if (col == 0){
        float* p = yacc + (t&3)*64 + b0w;    // accumulate partial y, slot t&3
        FADDF(p + 0, s0); FADDF(p + 1, s1);
        FADDF(p + 2, s2); FADDF(p + 3, s3);
      }
      // zero slot (t+2)&3 for reuse at step t+2: time-disjoint from all
      // fadds (step t-2 drained before role0 step t; step t+2 gated behind
      // role0 step t+1) and all reads (role0 step t+... gated via h-chain).
      if (tid < 64)
        ST1SCW(yacc + ((t+2)&3)*64 + tid, 0.f)
      drain_sync();
      if (tid < 32)                          // y flag -> role0 lines
        ASTORE(mbox + (tid*2 + 1)*32 + j, t + 1);
    }
  }

  // ---------------- finale: one global release/acquire barrier ------------
  gbar(gslots, epoch, wg, tid, 2);
  if (wg == 0 && tid < 64)                   // y[1023] in slot 1023&3 = 3
    out[(size_t)tid*TT + 1023] = fmaxf(ALDF(yacc + 3*64 + tid) + bo2v, 0.f);
  #pragma unroll
  for (int k = 0; k < 2; ++k){
    int g = wg*512 + k*256 + tid;
    if (g < 32768){                          // h0 final in buf0 planes
      out[65536 + g] = bf2f(hp[g]) + bf2f(hp[65536 + g]);
    } else {
      int g2 = g - 32768;                    // h1 planes
      out[65536 + g] = bf2f(hp[131072 + g2]) + bf2f(hp[163840 + g2]);
    }
  }
}

extern "C" void kernel_launch(void* const* d_in, const int* in_sizes, int n_in,
                              void* d_out, int out_size, void* d_ws, size_t ws_size,
                              hipStream_t stream){
  const float* ctx   = (const float*)d_in[0];
  const float* Wih0  = (const float*)d_in[2];
  const float* Whh0  = (const float*)d_in[3];
  const float* bih0  = (const float*)d_in[4];
  const float* bhh0  = (const float*)d_in[5];
  const float* Wih1  = (const float*)d_in[6];
  const float* Whh1  = (const float*)d_in[7];
  const float* bih1  = (const float*)d_in[8];
  const float* bhh1  = (const float*)d_in[9];
  const float* Wo1   = (const float*)d_in[10];
  const float* bo1   = (const float*)d_in[11];
  const float* Wo2   = (const float*)d_in[12];
  const float* bo2   = (const float*)d_in[13];

  (void)in_sizes; (void)n_in; (void)out_size; (void)ws_size;

  (void)hipFuncSetAttribute((const void*)decoder_rnn,
                            hipFuncAttributeMaxDynamicSharedMemorySize,
                            (int)sizeof(Smem));

  decoder_rnn<<<NWG, NT, sizeof(Smem), stream>>>(
      ctx, Wih0, Whh0, bih0, bhh0, Wih1, Whh1, bih1, bhh1,
      Wo1, bo1, Wo2, bo2, (float*)d_out, (float*)d_ws);
}

// Round 7
// 9780.877 us; speedup vs baseline: 1.4525x; 1.4525x over previous
//
#include <hip/hip_runtime.h>
#include <stdint.h>

// DecoderRNN R22: R19 protocol EXACTLY (counter flags via FADDI, tid0-poll
// waitmail + syncthreads, parity yout overwrite scheme) -- R21's waitvec
// multi-wave poll was an LLC hotspot (+1.65ms), reverted.
// NEW: 256 WGs = all 256 CUs. Batch-split every role into 2 independent
// half-batch pipelines (beta = wg>>7 owns 32 batches). Per-WG tile halves:
//  - role2/role3 (critical hops): 32KB h-load (was 64KB); waves = (bblk,
//    khalf) K-SPLIT -> per-wave LDS B-reads & MFMAs halve (48+48, was 96+96);
//    k-halves combined via small LDS buffer + syncthreads BEFORE the
//    nonlinearity.
//  - role0/role1 (off-critical / slack): waves 0,1 do full-K for their
//    b-block (fp32 accumulation order IDENTICAL to R19), waves 2,3 idle in
//    MFMA but help the loads' coalescing footprint via their own A-rows? No:
//    they simply idle; loads are per-lane in waves 0,1 (same as R19 shape).
// Flag topology identical per beta-machine: 32 producers per counter,
// targets 32t / 32(t+1); all lines offset by gid*128.

#define NWG 256
#define NT  256
#define TT  1024

typedef unsigned short ushort;
typedef unsigned int   uint;
typedef __attribute__((ext_vector_type(8))) short short8;
typedef __attribute__((ext_vector_type(4))) float f32x4;
typedef __attribute__((ext_vector_type(4))) uint  uint4v;

struct __align__(16) Smem {
  ushort wpl[2][48*520];
  float  gictx[3*16*68];     // per-WG: 48 rows x 32 local batches (stride 68)
  float  xk[2][64][16];      // k-half combine buffer [bblk][lane][slot]
  float  wcol[3][16];
  float  bsumR[16], bsumZ[16], binN[16], bhnN[16];
  float  bo1v[16], wo2v[16];
  float  prevS[64];          // use [0..32)
};

__device__ __forceinline__ float frcp(float x){
#if __has_builtin(__builtin_amdgcn_rcpf)
  return __builtin_amdgcn_rcpf(x);
#else
  return 1.f/x;
#endif
}
__device__ __forceinline__ float sigm(float x){ return frcp(1.f + __expf(-x)); }
__device__ __forceinline__ float tanh_f(float x){
  return 1.f - 2.f*frcp(__expf(2.f*x) + 1.f);
}
__device__ __forceinline__ float bf2f(ushort h){ return __uint_as_float(((uint)h)<<16); }
__device__ __forceinline__ ushort bfrnd(float x){
  uint u = __float_as_uint(x);
  return (ushort)((u + 0x7fffu + ((u>>16)&1u)) >> 16);
}
#define SWP(p, v)  (void)__hip_atomic_exchange((uint*)(p), (uint)(v), __ATOMIC_RELAXED, __HIP_MEMORY_SCOPE_AGENT)
#define ALD1(p)    __hip_atomic_load((const uint*)(p), __ATOMIC_RELAXED, __HIP_MEMORY_SCOPE_AGENT)
#define ALDF(p)    __uint_as_float(ALD1(p))
#define FADDI(p)   (void)__hip_atomic_fetch_add((p), 1, __ATOMIC_RELAXED, __HIP_MEMORY_SCOPE_AGENT)

// init/final global barrier (epoch-monotonic), 256 slots
__device__ __forceinline__ void gbar(int* slots, int* epoch, int w, int tid, int e){
  __syncthreads();
  if (tid == 0)
    __hip_atomic_store(&slots[w], e, __ATOMIC_RELEASE, __HIP_MEMORY_SCOPE_AGENT);
  if (w == 0 && tid < 64){
    for(;;){
      int m0 = __hip_atomic_load(&slots[tid*4+0], __ATOMIC_RELAXED, __HIP_MEMORY_SCOPE_AGENT);
      int m1 = __hip_atomic_load(&slots[tid*4+1], __ATOMIC_RELAXED, __HIP_MEMORY_SCOPE_AGENT);
      int m2 = __hip_atomic_load(&slots[tid*4+2], __ATOMIC_RELAXED, __HIP_MEMORY_SCOPE_AGENT);
      int m3 = __hip_atomic_load(&slots[tid*4+3], __ATOMIC_RELAXED, __HIP_MEMORY_SCOPE_AGENT);
      if (__all(min(min(m0,m1),min(m2,m3)) >= e)) break;
      __builtin_amdgcn_s_sleep(1);
    }
    if (tid == 0){
      __builtin_amdgcn_fence(__ATOMIC_ACQUIRE, "agent");
      __hip_atomic_store(epoch, e, __ATOMIC_RELEASE, __HIP_MEMORY_SCOPE_AGENT);
    }
  }
  if (tid == 0){
    while (__hip_atomic_load(epoch, __ATOMIC_RELAXED, __HIP_MEMORY_SCOPE_AGENT) < e)
      __builtin_amdgcn_s_sleep(1);
    __builtin_amdgcn_fence(__ATOMIC_ACQUIRE, "agent");
  }
  __syncthreads();
}

__device__ __forceinline__ void drain_sync(){
  __builtin_amdgcn_s_waitcnt(0);
  __syncthreads();
}
// consumer poll: 1 lane, 1 dword, busy (R19-proven shape)
__device__ __forceinline__ void waitmail(const int* w, int target, int tid){
  if (tid == 0)
    while ((int)ALD1(w) < target) {}
  __syncthreads();
}

// coherent LLC-direct ops (sc0 sc1 = bypass L1+L2, coalesced)
#define LD1SC(dst, addr) \
  asm volatile("global_load_dwordx4 %0, %1, off sc0 sc1" : "=v"(dst) : "v"(addr));
#define LD1SCD(dst, addr) \
  asm volatile("global_load_dword %0, %1, off sc0 sc1" : "=v"(dst) : "v"(addr));
#define STSH(addr, val) \
  asm volatile("global_store_short %0, %1, off sc0 sc1" :: "v"(addr), "v"(val) : "memory");
#define ST4SC(addr, val) \
  asm volatile("global_store_dwordx4 %0, %1, off sc0 sc1" :: "v"(addr), "v"(val) : "memory");
#define WB3(a,b,c) asm volatile("s_waitcnt vmcnt(0)" : "+v"(a),"+v"(b),"+v"(c));
#define VMBAR8(a,b,c,d,e,f,g,h) \
  asm volatile("s_waitcnt vmcnt(0)" \
               : "+v"(a),"+v"(b),"+v"(c),"+v"(d),"+v"(e),"+v"(f),"+v"(g),"+v"(h));

#define LDH(P, i) \
  asm volatile("global_load_dwordx4 %0, %1, off sc0 sc1" \
               : "=v"(ha##i) : "v"((P) + aoffB + (i)*32));
#define LDL(P, i) \
  asm volatile("global_load_dwordx4 %0, %1, off sc0 sc1" \
               : "=v"(la##i) : "v"((P) + aoffB + (i)*32));
#define LDH8(P, i) \
  asm volatile("global_load_dwordx4 %0, %1, off sc0 sc1" \
               : "=v"(ha##i) : "v"((P) + aoff8 + (i)*32));

// full-K hi+lo (roles 0/1, waves 0,1)
#define DECL_HILO(PH, PL) \
  uint4v ha0,ha1,ha2,ha3,ha4,ha5,ha6,ha7,ha8,ha9,ha10,ha11,ha12,ha13,ha14,ha15; \
  uint4v la0,la1,la2,la3,la4,la5,la6,la7,la8,la9,la10,la11,la12,la13,la14,la15; \
  LDH(PH,0) LDH(PH,1) LDH(PH,2) LDH(PH,3) LDH(PH,4) LDH(PH,5) LDH(PH,6) LDH(PH,7) \
  LDH(PH,8) LDH(PH,9) LDH(PH,10) LDH(PH,11) LDH(PH,12) LDH(PH,13) LDH(PH,14) LDH(PH,15) \
  LDL(PL,0) LDL(PL,1) LDL(PL,2) LDL(PL,3) LDL(PL,4) LDL(PL,5) LDL(PL,6) LDL(PL,7) \
  LDL(PL,8) LDL(PL,9) LDL(PL,10) LDL(PL,11) LDL(PL,12) LDL(PL,13) LDL(PL,14) LDL(PL,15) \
  VMBAR8(ha0,ha1,ha2,ha3,ha4,ha5,ha6,ha7) \
  VMBAR8(ha8,ha9,ha10,ha11,ha12,ha13,ha14,ha15) \
  VMBAR8(la0,la1,la2,la3,la4,la5,la6,la7) \
  VMBAR8(la8,la9,la10,la11,la12,la13,la14,la15)

// k-half hi-only (roles 2/3, all waves; aoff8 already includes kbase)
#define DECL_HI8(P) \
  uint4v ha0,ha1,ha2,ha3,ha4,ha5,ha6,ha7; \
  LDH8(P,0) LDH8(P,1) LDH8(P,2) LDH8(P,3) LDH8(P,4) LDH8(P,5) LDH8(P,6) LDH8(P,7) \
  VMBAR8(ha0,ha1,ha2,ha3,ha4,ha5,ha6,ha7)

#define MFMA_ __builtin_amdgcn_mfma_f32_16x16x32_bf16

// full precision full-K (roles 0/1): 9 MFMAs per i
#define MS3F(i) { \
  short8 AH_ = __builtin_bit_cast(short8, ha##i); \
  short8 AL_ = __builtin_bit_cast(short8, la##i); \
  const int ko_ = (i)*32 + q*8; \
  short8 bh_ = *(const short8*)(&S.wpl[0][(col)*520 + ko_]); \
  short8 bl_ = *(const short8*)(&S.wpl[1][(col)*520 + ko_]); \
  acc0 = MFMA_(AH_, bh_, acc0, 0,0,0); \
  acc0 = MFMA_(AL_, bh_, acc0, 0,0,0); \
  acc0 = MFMA_(AH_, bl_, acc0, 0,0,0); \
  bh_ = *(const short8*)(&S.wpl[0][(16+col)*520 + ko_]); \
  bl_ = *(const short8*)(&S.wpl[1][(16+col)*520 + ko_]); \
  acc1 = MFMA_(AH_, bh_, acc1, 0,0,0); \
  acc1 = MFMA_(AL_, bh_, acc1, 0,0,0); \
  acc1 = MFMA_(AH_, bl_, acc1, 0,0,0); \
  bh_ = *(const short8*)(&S.wpl[0][(32+col)*520 + ko_]); \
  bl_ = *(const short8*)(&S.wpl[1][(32+col)*520 + ko_]); \
  acc2 = MFMA_(AH_, bh_, acc2, 0,0,0); \
  acc2 = MFMA_(AL_, bh_, acc2, 0,0,0); \
  acc2 = MFMA_(AH_, bl_, acc2, 0,0,0); }

// hi-only k-half (role 2): 6 MFMAs per i; kb = khalf*256
#define MS3H(i) { \
  short8 AH_ = __builtin_bit_cast(short8, ha##i); \
  const int ko_ = kb + (i)*32 + q*8; \
  short8 bh_ = *(const short8*)(&S.wpl[0][(col)*520 + ko_]); \
  short8 bl_ = *(const short8*)(&S.wpl[1][(col)*520 + ko_]); \
  acc0 = MFMA_(AH_, bh_, acc0, 0,0,0); \
  acc0 = MFMA_(AH_, bl_, acc0, 0,0,0); \
  bh_ = *(const short8*)(&S.wpl[0][(16+col)*520 + ko_]); \
  bl_ = *(const short8*)(&S.wpl[1][(16+col)*520 + ko_]); \
  acc1 = MFMA_(AH_, bh_, acc1, 0,0,0); \
  acc1 = MFMA_(AH_, bl_, acc1, 0,0,0); \
  bh_ = *(const short8*)(&S.wpl[0][(32+col)*520 + ko_]); \
  bl_ = *(const short8*)(&S.wpl[1][(32+col)*520 + ko_]); \
  acc2 = MFMA_(AH_, bh_, acc2, 0,0,0); \
  acc2 = MFMA_(AH_, bl_, acc2, 0,0,0); }

// hi-only k-half, single output block (role 3): 2 MFMAs per i
#define MS1H(i) { \
  short8 AH_ = __builtin_bit_cast(short8, ha##i); \
  const int ko_ = kb + (i)*32 + q*8; \
  short8 bh_ = *(const short8*)(&S.wpl[0][(col)*520 + ko_]); \
  short8 bl_ = *(const short8*)(&S.wpl[1][(col)*520 + ko_]); \
  acc0 = MFMA_(AH_, bh_, acc0, 0,0,0); \
  acc0 = MFMA_(AH_, bl_, acc0, 0,0,0); }

#define RUN16(M) M(0) M(1) M(2) M(3) M(4) M(5) M(6) M(7) \
                 M(8) M(9) M(10) M(11) M(12) M(13) M(14) M(15)
#define RUN8(M)  M(0) M(1) M(2) M(3) M(4) M(5) M(6) M(7)

extern "C" __global__ void __launch_bounds__(NT, 1)
decoder_rnn(const float* __restrict__ ctx,   // [64][512]
            const float* __restrict__ Wih0,  // [1536][513] (row stride 513!)
            const float* __restrict__ Whh0,
            const float* __restrict__ bih0,
            const float* __restrict__ bhh0g,
            const float* __restrict__ Wih1,
            const float* __restrict__ Whh1,
            const float* __restrict__ bih1g,
            const float* __restrict__ bhh1g,
            const float* __restrict__ Wo1,
            const float* __restrict__ bo1g,
            const float* __restrict__ Wo2,
            const float* __restrict__ bo2g,
            float* __restrict__ out,         // [64*1024 y][65536 h_i]
            float* __restrict__ ws)
{
  extern __shared__ char smem_raw[];
  Smem& S = *reinterpret_cast<Smem*>(smem_raw);
  const int tid = threadIdx.x;
  const int wg  = blockIdx.x;

  ushort* hp    = (ushort*)ws;               // h0hi[2]@0/32768, h0lo[2]@65536/
                                             // 98304, h1hi@131072, h1lo@163840
  float* gh1raw = (float*)ws + 98304;        // 64 WGs x 1536 floats
  float* yout   = (float*)ws + 196608;       // 2 x 2048 (jm*64 + global b)
  int*   ibase  = (int*)((float*)ws + 200704);
  int*   gslots = ibase;                     // [256] gbar
  int*   epoch  = ibase + 256;
  int*   mbox   = ibase + 512;               // 256 lines x 32 ints

  const float bo2v = bo2g[0];

  // ---------------- init (swaps -> LLC; once, off critical path) ----------
  for (int i = wg*NT + tid; i < 200704; i += NWG*NT)
    SWP((uint*)ws + i, 0u);
  if (wg == 0)
    for (int i = tid; i < 256*32; i += NT) SWP(mbox + i, 0);

  const int gid   = wg >> 7;                 // batch half (2 indep machines)
  const int w128  = wg & 127;
  const int role  = w128 >> 5;
  const int j     = w128 & 31;
  const int bbase = 32*gid;

  if (role != 3){
    const float* Wsrc = (role == 0) ? Whh0 : (role == 1) ? Whh1 : Wih1;
    for (int i = tid; i < 48*512; i += NT){
      int r = i >> 9, k = i & 511;
      int g = r >> 4, n = r & 15;
      float wv = Wsrc[(size_t)(g*512 + 16*j + n)*512 + k];
      ushort hh = bfrnd(wv);
      S.wpl[0][r*520 + k] = hh;
      S.wpl[1][r*520 + k] = bfrnd(wv - bf2f(hh));
    }
  } else {
    for (int i = tid; i < 16*512; i += NT){
      int r = i >> 9, k = i & 511;
      float wv = Wo1[(size_t)(16*j + r)*512 + k];
      ushort hh = bfrnd(wv);
      S.wpl[0][r*520 + k] = hh;
      S.wpl[1][r*520 + k] = bfrnd(wv - bf2f(hh));
    }
    if (tid < 16){ S.bo1v[tid] = bo1g[16*j + tid]; S.wo2v[tid] = Wo2[16*j + tid]; }
  }
  if (role == 0){
    if (tid < 48){
      int g = tid >> 4, n = tid & 15;
      S.wcol[g][n] = Wih0[(size_t)(g*512 + 16*j + n)*513 + 512];
    }
    if (tid < 16) S.bhnN[tid] = bhh0g[2*512 + 16*j + tid];
    for (int idx = tid; idx < 1536; idx += NT){   // 48 rows x 32 local b
      int r = idx >> 5, bl = idx & 31;
      int g = r >> 4, n = r & 15;
      int grow = g*512 + 16*j + n;
      const float* wr = Wih0 + (size_t)grow*513;
      const float* cx = ctx  + (size_t)(bbase + bl)*512;
      float s = bih0[grow];
      if (g < 2) s += bhh0g[grow];
      #pragma unroll 4
      for (int k = 0; k < 512; ++k) s += wr[k]*cx[k];
      S.gictx[g*1088 + n*68 + bl] = s;
    }
  }
  if (role == 2 && tid < 16){
    int n = tid;
    S.bsumR[n] = bih1g[16*j + n]       + bhh1g[16*j + n];
    S.bsumZ[n] = bih1g[512 + 16*j + n] + bhh1g[512 + 16*j + n];
    S.binN[n]  = bih1g[1024 + 16*j + n];
    S.bhnN[n]  = bhh1g[1024 + 16*j + n];
  }

  gbar(gslots, epoch, wg, tid, 1);

  int* myline = mbox + wg*32;                // flags: [0] data, [1] secondary

  const int v    = tid >> 6;
  const int l    = tid & 63;
  const int q    = l >> 4;
  const int col  = l & 15;
  const int bblk = v & 1;
  const int kb   = (v >> 1)*256;             // k-half base (roles 2/3)
  const int aoffB = (bbase + 16*bblk + col)*512 + q*8;         // full-K lanes
  const int aoff8 = (bbase + 16*bblk + col)*512 + kb + q*8;    // k-half lanes
  const int b0wL  = 16*bblk + 4*q;           // local batch row base (waves 0,1)
  const int ng    = 16*j + col;

  if (role == 0){
    float hc0 = 0.f, hc1 = 0.f, hc2 = 0.f, hc3 = 0.f;   // carried h0-old (fp32)
    for (int t = 0; t < TT; ++t){
      const int r0 = t & 1, w0 = r0 ^ 1;
      waitmail(myline + 0, 32*t, tid);       // h0[t-1] (this beta) at LLC
      const ushort* rH = hp + r0*32768;
      const ushort* rL = hp + 65536 + r0*32768;
      ushort*       wH = hp + w0*32768;
      ushort*       wL = hp + 65536 + w0*32768;
      f32x4 acc0={0,0,0,0}, acc1={0,0,0,0}, acc2={0,0,0,0};
      if (v < 2){
        DECL_HILO(rH, rL)
        RUN16(MS3F)
      }
      waitmail(myline + 1, 32*t, tid);       // y[t-1] partials at LLC
      if (tid < 32){
        float s = 0.f;
        if (t > 0){
          const float* yp = yout + ((t-1)&1)*2048 + bbase + tid;
          float vv[32];
          #pragma unroll
          for (int jj = 0; jj < 32; ++jj)
            LD1SCD(vv[jj], yp + jj*64)
          VMBAR8(vv[0],vv[1],vv[2],vv[3],vv[4],vv[5],vv[6],vv[7])
          VMBAR8(vv[8],vv[9],vv[10],vv[11],vv[12],vv[13],vv[14],vv[15])
          VMBAR8(vv[16],vv[17],vv[18],vv[19],vv[20],vv[21],vv[22],vv[23])
          VMBAR8(vv[24],vv[25],vv[26],vv[27],vv[28],vv[29],vv[30],vv[31])
          #pragma unroll
          for (int jj = 0; jj < 32; ++jj) s += vv[jj];
        }
        float pv = fmaxf(s + bo2v, 0.f);
        S.prevS[tid] = pv;
        if (j == 0 && t > 0) out[(size_t)(bbase + tid)*TT + (t-1)] = pv;
      }
      __syncthreads();
      if (v < 2){
        f32x4 pv4 = *(const f32x4*)&S.prevS[b0wL];
        f32x4 gR = *(const f32x4*)&S.gictx[0*1088 + col*68 + b0wL];
        f32x4 gZ = *(const f32x4*)&S.gictx[1*1088 + col*68 + b0wL];
        f32x4 gN = *(const f32x4*)&S.gictx[2*1088 + col*68 + b0wL];
        float wc0 = S.wcol[0][col], wc1 = S.wcol[1][col], wc2 = S.wcol[2][col];
        float bhn = S.bhnN[col];
        #define E0(i, HC) { \
          float rr = sigm(gR[i] + pv4[i]*wc0 + acc0[i]); \
          float zz = sigm(gZ[i] + pv4[i]*wc1 + acc1[i]); \
          float nn = tanh_f(gN[i] + pv4[i]*wc2 + rr*(acc2[i] + bhn)); \
          float h = (1.f-zz)*nn + zz*HC; \
          HC = h; \
          ushort hh_ = bfrnd(h); \
          uint hu_ = hh_, lu_ = bfrnd(h - bf2f(hh_)); \
          STSH(wH + (size_t)(bbase + b0wL + (i))*512 + ng, hu_) \
          STSH(wL + (size_t)(bbase + b0wL + (i))*512 + ng, lu_) }
        E0(0,hc0) E0(1,hc1) E0(2,hc2) E0(3,hc3)
        #undef E0
      }
      drain_sync();
      if (tid < 64){                         // -> role0(beta) + role2(beta)
        int c = tid & 31;
        int cline = (tid < 32) ? (gid*128 + c) : (gid*128 + 64 + c);
        FADDI(mbox + cline*32 + 0);
      }
    }
  } else if (role == 1){
    const ushort* rH = hp + 131072;          // h1 hi plane
    const ushort* rL = hp + 163840;          // h1 lo plane
    float* gbase = gh1raw + (size_t)(gid*32 + j)*1536;
    for (int t = 0; t < TT; ++t){
      waitmail(myline + 0, 32*t, tid);       // h1[t-1] (this beta) at LLC
      if (v < 2){
        f32x4 acc0={0,0,0,0}, acc1={0,0,0,0}, acc2={0,0,0,0};
        DECL_HILO(rH, rL)
        RUN16(MS3F)
        float* gp = gbase + v*256 + l*4;
        ST4SC(gp,         acc0)
        ST4SC(gp + 512,   acc1)
        ST4SC(gp + 1024,  acc2)
      }
      drain_sync();
      if (tid < 32)                          // -> role2(beta) gh1 counters
        FADDI(mbox + (gid*128 + 64 + tid)*32 + 1);
    }
  } else if (role == 2){
    ushort* p1H = hp + 131072;
    ushort* p1L = hp + 163840;
    const float* gbase = gh1raw + (size_t)(gid*32 + j)*1536;
    float hc0 = 0.f, hc1 = 0.f, hc2 = 0.f, hc3 = 0.f;   // carried h1-old (fp32)
    for (int t = 0; t < TT; ++t){
      const int w0 = (t & 1) ^ 1;
      waitmail(myline + 0, 32*(t+1), tid);   // h0[t] (this beta) at LLC
      waitmail(myline + 1, 32*(t+1), tid);   // gh1[t] (slack: ~always set)
      const ushort* rH = hp + w0*32768;      // h0[t] hi plane ONLY (critical)
      uint4v hRv, hZv, hNv;
      f32x4 acc0={0,0,0,0}, acc1={0,0,0,0}, acc2={0,0,0,0};
      if (v < 2){                            // gh1 loads overlap A-loads
        const float* gp = gbase + v*256 + l*4;
        LD1SC(hRv, (const uint*)(gp + 0))
        LD1SC(hZv, (const uint*)(gp + 512))
        LD1SC(hNv, (const uint*)(gp + 1024))
      }
      {
        DECL_HI8(rH)                         // all 4 waves: k-half A
        RUN8(MS3H)
      }
      if (v >= 2){                           // stash k-half partials
        *(f32x4*)&S.xk[bblk][l][0] = acc0;
        *(f32x4*)&S.xk[bblk][l][4] = acc1;
        *(f32x4*)&S.xk[bblk][l][8] = acc2;
      }
      __syncthreads();
      if (v < 2){
        f32x4 xa = *(const f32x4*)&S.xk[bblk][l][0];
        f32x4 xb = *(const f32x4*)&S.xk[bblk][l][4];
        f32x4 xc = *(const f32x4*)&S.xk[bblk][l][8];
        acc0 += xa; acc1 += xb; acc2 += xc;
        WB3(hRv, hZv, hNv)
        f32x4 hR = __builtin_bit_cast(f32x4, hRv);
        f32x4 hZ = __builtin_bit_cast(f32x4, hZv);
        f32x4 hN = __builtin_bit_cast(f32x4, hNv);
        float bsR = S.bsumR[col], bsZ = S.bsumZ[col];
        float biN = S.binN[col],  bhN = S.bhnN[col];
        #define E1(i, HC) { \
          float r1 = sigm(acc0[i] + hR[i] + bsR); \
          float z1 = sigm(acc1[i] + hZ[i] + bsZ); \
          float n1 = tanh_f(acc2[i] + biN + r1*(hN[i] + bhN)); \
          float h = (1.f-z1)*n1 + z1*HC; \
          HC = h; \
          ushort hh_ = bfrnd(h); \
          uint hu_ = hh_, lu_ = bfrnd(h - bf2f(hh_)); \
          STSH(p1H + (size_t)(bbase + b0wL + (i))*512 + ng, hu_) \
          STSH(p1L + (size_t)(bbase + b0wL + (i))*512 + ng, lu_) }
        E1(0,hc0) E1(1,hc1) E1(2,hc2) E1(3,hc3)
        #undef E1
      }
      drain_sync();
      if (tid < 64){                         // -> role1(beta) + role3(beta)
        int c = tid & 31;
        int cline = (tid < 32) ? (gid*128 + 32 + c) : (gid*128 + 96 + c);
        FADDI(mbox + cline*32 + 0);
      }
    }
  } else {
    const ushort* rH = hp + 131072;          // h1 hi plane ONLY (critical)
    for (int t = 0; t < TT; ++t){
      waitmail(myline + 0, 32*(t+1), tid);   // h1[t] (this beta) at LLC
      f32x4 acc0={0,0,0,0};
      {
        DECL_HI8(rH)
        RUN8(MS1H)
      }
      if (v >= 2)
        *(f32x4*)&S.xk[bblk][l][0] = acc0;
      __syncthreads();
      if (v < 2){
        f32x4 xa = *(const f32x4*)&S.xk[bblk][l][0];
        acc0 += xa;                          // full z (both k-halves)
        float s0 = S.wo2v[col]*fmaxf(acc0[0] + S.bo1v[col], 0.f);
        float s1 = S.wo2v[col]*fmaxf(acc0[1] + S.bo1v[col], 0.f);
        float s2 = S.wo2v[col]*fmaxf(acc0[2] + S.bo1v[col], 0.f);
        float s3 = S.wo2v[col]*fmaxf(acc0[3] + S.bo1v[col], 0.f);
        #pragma unroll
        for (int d = 1; d < 16; d <<= 1){
          s0 += __shfl_xor(s0, d);
          s1 += __shfl_xor(s1, d);
          s2 += __shfl_xor(s2, d);
          s3 += __shfl_xor(s3, d);
        }
        if (col == 0){
          float* rp = yout + (t&1)*2048 + j*64 + bbase + b0wL;
          f32x4 sv = {s0, s1, s2, s3};
          ST4SC(rp, sv)
        }
      }
      drain_sync();
      if (tid < 32)                          // -> role0(beta) y counters
        FADDI(mbox + (gid*128 + tid)*32 + 1);
    }
  }

  // ---------------- finale: one global release/acquire barrier ------------
  gbar(gslots, epoch, wg, tid, 2);
  if (wg == 0 && tid < 64){
    float s = 0.f;
    const float* yp = yout + 2048 + tid;     // parity of t=1023 is 1
    #pragma unroll
    for (int jj = 0; jj < 32; ++jj) s += ALDF(yp + jj*64);
    out[(size_t)tid*TT + 1023] = fmaxf(s + bo2v, 0.f);
  }
  {
    int g = wg*256 + tid;                    // 256 WGs x 256 thr = 65536
    if (g < 32768) out[65536 + g] = bf2f(hp[g]) + bf2f(hp[65536 + g]);
    else {
      int g2 = g - 32768;
      out[65536 + g] = bf2f(hp[131072 + g2]) + bf2f(hp[163840 + g2]);
    }
  }
}

extern "C" void kernel_launch(void* const* d_in, const int* in_sizes, int n_in,
                              void* d_out, int out_size, void* d_ws, size_t ws_size,
                              hipStream_t stream){
  const float* ctx   = (const float*)d_in[0];
  const float* Wih0  = (const float*)d_in[2];
  const float* Whh0  = (const float*)d_in[3];
  const float* bih0  = (const float*)d_in[4];
  const float* bhh0  = (const float*)d_in[5];
  const float* Wih1  = (const float*)d_in[6];
  const float* Whh1  = (const float*)d_in[7];
  const float* bih1  = (const float*)d_in[8];
  const float* bhh1  = (const float*)d_in[9];
  const float* Wo1   = (const float*)d_in[10];
  const float* bo1   = (const float*)d_in[11];
  const float* Wo2   = (const float*)d_in[12];
  const float* bo2   = (const float*)d_in[13];

  (void)in_sizes; (void)n_in; (void)out_size; (void)ws_size;

  (void)hipFuncSetAttribute((const void*)decoder_rnn,
                            hipFuncAttributeMaxDynamicSharedMemorySize,
                            (int)sizeof(Smem));

  decoder_rnn<<<NWG, NT, sizeof(Smem), stream>>>(
      ctx, Wih0, Whh0, bih0, bhh0, Wih1, Whh1, bih1, bhh1,
      Wo1, bo1, Wo2, bo2, (float*)d_out, (float*)d_ws);
}

// Round 8
// 8770.102 us; speedup vs baseline: 1.6199x; 1.1153x over previous
//
#include <hip/hip_runtime.h>
#include <stdint.h>

// DecoderRNN R23: R22 base (9.78ms) + role1 ELIMINATED (role2 computes gh1
// itself in the h0-wait slack window) + freed 64 WGs double role2's split:
//  per machine: role0 x32 (32b x 16c), role2 x64 (16b x 16c, 4-way K-split),
//  role3 x32 (32b, 2-way K-split). 256 WGs total.
//  role2 per step: [wait h1[t-1] own-half] -> load h1 hi+lo (own 16 batches,
//  k-quarter/wave) -> 36 MFMA gh1 (full precision) -> [wait h0[t]] -> load
//  h0 hi (4 dwordx4/lane) -> 12 MFMA gi (hi x hi) -> LDS combine -> EW ->
//  store h1 -> drain -> flag. gh1 phase hides under the ~2-hop h0 slack.
//  Wih1 stored HI-ONLY in LDS (162.3KB budget); Whh1 keeps hi/lo; n-gate
//  keeps gi/gh accumulators separate (GRU r*gh_n structure).
//  h1 flags: two counters (bh groups, 32 producers each); role2 polls own
//  half, role3 polls both. gh1raw buffer gone.
// Protocol shape (FADDI counters, tid0-poll + syncthreads, drain-then-flag)
// is R19/R22-proven; R21's multi-wave poll hotspot not repeated.

#define NWG 256
#define NT  256
#define TT  1024

typedef unsigned short ushort;
typedef unsigned int   uint;
typedef __attribute__((ext_vector_type(8))) short short8;
typedef __attribute__((ext_vector_type(4))) float f32x4;
typedef __attribute__((ext_vector_type(4))) uint  uint4v;

struct __align__(16) SmemR0 {
  ushort wpl[2][48*520];     // Whh0 hi/lo
  float  gictx[3*16*68];
  float  wcol[3][16];
  float  bhnN[16];
  float  prevS[64];          // [0..32) used
};
struct __align__(16) SmemR2 {
  ushort whh[2][48*520];     // Whh1 hi/lo (full precision, self-recurrence)
  ushort wih[48*520];        // Wih1 HI ONLY (critical path)
  float  xk[3][64][16];      // k-quarter combine: {R,Z,Ni,Nh} x4
  float  bsumR[16], bsumZ[16], binN[16], bhnN[16];
};
struct __align__(16) SmemR3 {
  ushort wpl[2][16*520];     // Wo1 block hi/lo
  float  xk[2][64][4];
  float  bo1v[16], wo2v[16];
};

__device__ __forceinline__ float frcp(float x){
#if __has_builtin(__builtin_amdgcn_rcpf)
  return __builtin_amdgcn_rcpf(x);
#else
  return 1.f/x;
#endif
}
__device__ __forceinline__ float sigm(float x){ return frcp(1.f + __expf(-x)); }
__device__ __forceinline__ float tanh_f(float x){
  return 1.f - 2.f*frcp(__expf(2.f*x) + 1.f);
}
__device__ __forceinline__ float bf2f(ushort h){ return __uint_as_float(((uint)h)<<16); }
__device__ __forceinline__ ushort bfrnd(float x){
  uint u = __float_as_uint(x);
  return (ushort)((u + 0x7fffu + ((u>>16)&1u)) >> 16);
}
#define SWP(p, v)  (void)__hip_atomic_exchange((uint*)(p), (uint)(v), __ATOMIC_RELAXED, __HIP_MEMORY_SCOPE_AGENT)
#define ALD1(p)    __hip_atomic_load((const uint*)(p), __ATOMIC_RELAXED, __HIP_MEMORY_SCOPE_AGENT)
#define ALDF(p)    __uint_as_float(ALD1(p))
#define FADDI(p)   (void)__hip_atomic_fetch_add((p), 1, __ATOMIC_RELAXED, __HIP_MEMORY_SCOPE_AGENT)

__device__ __forceinline__ void gbar(int* slots, int* epoch, int w, int tid, int e){
  __syncthreads();
  if (tid == 0)
    __hip_atomic_store(&slots[w], e, __ATOMIC_RELEASE, __HIP_MEMORY_SCOPE_AGENT);
  if (w == 0 && tid < 64){
    for(;;){
      int m0 = __hip_atomic_load(&slots[tid*4+0], __ATOMIC_RELAXED, __HIP_MEMORY_SCOPE_AGENT);
      int m1 = __hip_atomic_load(&slots[tid*4+1], __ATOMIC_RELAXED, __HIP_MEMORY_SCOPE_AGENT);
      int m2 = __hip_atomic_load(&slots[tid*4+2], __ATOMIC_RELAXED, __HIP_MEMORY_SCOPE_AGENT);
      int m3 = __hip_atomic_load(&slots[tid*4+3], __ATOMIC_RELAXED, __HIP_MEMORY_SCOPE_AGENT);
      if (__all(min(min(m0,m1),min(m2,m3)) >= e)) break;
      __builtin_amdgcn_s_sleep(1);
    }
    if (tid == 0){
      __builtin_amdgcn_fence(__ATOMIC_ACQUIRE, "agent");
      __hip_atomic_store(epoch, e, __ATOMIC_RELEASE, __HIP_MEMORY_SCOPE_AGENT);
    }
  }
  if (tid == 0){
    while (__hip_atomic_load(epoch, __ATOMIC_RELAXED, __HIP_MEMORY_SCOPE_AGENT) < e)
      __builtin_amdgcn_s_sleep(1);
    __builtin_amdgcn_fence(__ATOMIC_ACQUIRE, "agent");
  }
  __syncthreads();
}

__device__ __forceinline__ void drain_sync(){
  __builtin_amdgcn_s_waitcnt(0);
  __syncthreads();
}
__device__ __forceinline__ void waitmail(const int* w, int target, int tid){
  if (tid == 0)
    while ((int)ALD1(w) < target) {}
  __syncthreads();
}
__device__ __forceinline__ void waitmail2(const int* a, const int* b, int target, int tid){
  if (tid == 0)
    while ((int)ALD1(a) < target || (int)ALD1(b) < target) {}
  __syncthreads();
}

// coherent LLC-direct ops (sc0 sc1 = bypass L1+L2, coalesced)
#define LD1SCD(dst, addr) \
  asm volatile("global_load_dword %0, %1, off sc0 sc1" : "=v"(dst) : "v"(addr));
#define STSH(addr, val) \
  asm volatile("global_store_short %0, %1, off sc0 sc1" :: "v"(addr), "v"(val) : "memory");
#define ST4SC(addr, val) \
  asm volatile("global_store_dwordx4 %0, %1, off sc0 sc1" :: "v"(addr), "v"(val) : "memory");
#define LD4A(DST, P, OFS) \
  asm volatile("global_load_dwordx4 %0, %1, off sc0 sc1" : "=v"(DST) : "v"((P) + (OFS)));
#define VMBAR4(a,b,c,d) \
  asm volatile("s_waitcnt vmcnt(0)" : "+v"(a),"+v"(b),"+v"(c),"+v"(d));
#define VMBAR8(a,b,c,d,e,f,g,h) \
  asm volatile("s_waitcnt vmcnt(0)" \
               : "+v"(a),"+v"(b),"+v"(c),"+v"(d),"+v"(e),"+v"(f),"+v"(g),"+v"(h));

#define MFMA_ __builtin_amdgcn_mfma_f32_16x16x32_bf16

// ---------------- role0: full-K hi/lo (waves 0,1) ----------------
#define DECL_HILO(PH, PL) \
  uint4v ha0,ha1,ha2,ha3,ha4,ha5,ha6,ha7,ha8,ha9,ha10,ha11,ha12,ha13,ha14,ha15; \
  uint4v la0,la1,la2,la3,la4,la5,la6,la7,la8,la9,la10,la11,la12,la13,la14,la15; \
  LD4A(ha0,PH,aoffB+0*32) LD4A(ha1,PH,aoffB+1*32) LD4A(ha2,PH,aoffB+2*32) LD4A(ha3,PH,aoffB+3*32) \
  LD4A(ha4,PH,aoffB+4*32) LD4A(ha5,PH,aoffB+5*32) LD4A(ha6,PH,aoffB+6*32) LD4A(ha7,PH,aoffB+7*32) \
  LD4A(ha8,PH,aoffB+8*32) LD4A(ha9,PH,aoffB+9*32) LD4A(ha10,PH,aoffB+10*32) LD4A(ha11,PH,aoffB+11*32) \
  LD4A(ha12,PH,aoffB+12*32) LD4A(ha13,PH,aoffB+13*32) LD4A(ha14,PH,aoffB+14*32) LD4A(ha15,PH,aoffB+15*32) \
  LD4A(la0,PL,aoffB+0*32) LD4A(la1,PL,aoffB+1*32) LD4A(la2,PL,aoffB+2*32) LD4A(la3,PL,aoffB+3*32) \
  LD4A(la4,PL,aoffB+4*32) LD4A(la5,PL,aoffB+5*32) LD4A(la6,PL,aoffB+6*32) LD4A(la7,PL,aoffB+7*32) \
  LD4A(la8,PL,aoffB+8*32) LD4A(la9,PL,aoffB+9*32) LD4A(la10,PL,aoffB+10*32) LD4A(la11,PL,aoffB+11*32) \
  LD4A(la12,PL,aoffB+12*32) LD4A(la13,PL,aoffB+13*32) LD4A(la14,PL,aoffB+14*32) LD4A(la15,PL,aoffB+15*32) \
  VMBAR8(ha0,ha1,ha2,ha3,ha4,ha5,ha6,ha7) \
  VMBAR8(ha8,ha9,ha10,ha11,ha12,ha13,ha14,ha15) \
  VMBAR8(la0,la1,la2,la3,la4,la5,la6,la7) \
  VMBAR8(la8,la9,la10,la11,la12,la13,la14,la15)

#define MS3F(i) { \
  short8 AH_ = __builtin_bit_cast(short8, ha##i); \
  short8 AL_ = __builtin_bit_cast(short8, la##i); \
  const int ko_ = (i)*32 + q*8; \
  short8 bh_ = *(const short8*)(&S0.wpl[0][(col)*520 + ko_]); \
  short8 bl_ = *(const short8*)(&S0.wpl[1][(col)*520 + ko_]); \
  acc0 = MFMA_(AH_, bh_, acc0, 0,0,0); \
  acc0 = MFMA_(AL_, bh_, acc0, 0,0,0); \
  acc0 = MFMA_(AH_, bl_, acc0, 0,0,0); \
  bh_ = *(const short8*)(&S0.wpl[0][(16+col)*520 + ko_]); \
  bl_ = *(const short8*)(&S0.wpl[1][(16+col)*520 + ko_]); \
  acc1 = MFMA_(AH_, bh_, acc1, 0,0,0); \
  acc1 = MFMA_(AL_, bh_, acc1, 0,0,0); \
  acc1 = MFMA_(AH_, bl_, acc1, 0,0,0); \
  bh_ = *(const short8*)(&S0.wpl[0][(32+col)*520 + ko_]); \
  bl_ = *(const short8*)(&S0.wpl[1][(32+col)*520 + ko_]); \
  acc2 = MFMA_(AH_, bh_, acc2, 0,0,0); \
  acc2 = MFMA_(AL_, bh_, acc2, 0,0,0); \
  acc2 = MFMA_(AH_, bl_, acc2, 0,0,0); }

// ---------------- role2: gh1 full (hi/lo A,B) + gi (hi A, hi B) ----------
#define GH1(i) { \
  short8 AH_ = __builtin_bit_cast(short8, ha##i); \
  short8 AL_ = __builtin_bit_cast(short8, la##i); \
  const int ko_ = kq + (i)*32 + q*8; \
  short8 bh_ = *(const short8*)(&S2.whh[0][(col)*520 + ko_]); \
  short8 bl_ = *(const short8*)(&S2.whh[1][(col)*520 + ko_]); \
  aR = MFMA_(AH_, bh_, aR, 0,0,0); \
  aR = MFMA_(AL_, bh_, aR, 0,0,0); \
  aR = MFMA_(AH_, bl_, aR, 0,0,0); \
  bh_ = *(const short8*)(&S2.whh[0][(16+col)*520 + ko_]); \
  bl_ = *(const short8*)(&S2.whh[1][(16+col)*520 + ko_]); \
  aZ = MFMA_(AH_, bh_, aZ, 0,0,0); \
  aZ = MFMA_(AL_, bh_, aZ, 0,0,0); \
  aZ = MFMA_(AH_, bl_, aZ, 0,0,0); \
  bh_ = *(const short8*)(&S2.whh[0][(32+col)*520 + ko_]); \
  bl_ = *(const short8*)(&S2.whh[1][(32+col)*520 + ko_]); \
  aNh = MFMA_(AH_, bh_, aNh, 0,0,0); \
  aNh = MFMA_(AL_, bh_, aNh, 0,0,0); \
  aNh = MFMA_(AH_, bl_, aNh, 0,0,0); }

#define GI1(i) { \
  short8 AH_ = __builtin_bit_cast(short8, ga##i); \
  const int ko_ = kq + (i)*32 + q*8; \
  short8 bh_ = *(const short8*)(&S2.wih[(col)*520 + ko_]); \
  aR = MFMA_(AH_, bh_, aR, 0,0,0); \
  bh_ = *(const short8*)(&S2.wih[(16+col)*520 + ko_]); \
  aZ = MFMA_(AH_, bh_, aZ, 0,0,0); \
  bh_ = *(const short8*)(&S2.wih[(32+col)*520 + ko_]); \
  aNi = MFMA_(AH_, bh_, aNi, 0,0,0); }

// ---------------- role3: k-half hi A, hi/lo B -----------------------------
#define DECL_HI8(P) \
  uint4v ha0,ha1,ha2,ha3,ha4,ha5,ha6,ha7; \
  LD4A(ha0,P,aoff8+0*32) LD4A(ha1,P,aoff8+1*32) LD4A(ha2,P,aoff8+2*32) LD4A(ha3,P,aoff8+3*32) \
  LD4A(ha4,P,aoff8+4*32) LD4A(ha5,P,aoff8+5*32) LD4A(ha6,P,aoff8+6*32) LD4A(ha7,P,aoff8+7*32) \
  VMBAR8(ha0,ha1,ha2,ha3,ha4,ha5,ha6,ha7)

#define MS1H(i) { \
  short8 AH_ = __builtin_bit_cast(short8, ha##i); \
  const int ko_ = kb + (i)*32 + q*8; \
  short8 bh_ = *(const short8*)(&S3.wpl[0][(col)*520 + ko_]); \
  short8 bl_ = *(const short8*)(&S3.wpl[1][(col)*520 + ko_]); \
  acc0 = MFMA_(AH_, bh_, acc0, 0,0,0); \
  acc0 = MFMA_(AH_, bl_, acc0, 0,0,0); }

#define RUN16(M) M(0) M(1) M(2) M(3) M(4) M(5) M(6) M(7) \
                 M(8) M(9) M(10) M(11) M(12) M(13) M(14) M(15)
#define RUN8(M)  M(0) M(1) M(2) M(3) M(4) M(5) M(6) M(7)
#define RUN4(M)  M(0) M(1) M(2) M(3)

extern "C" __global__ void __launch_bounds__(NT, 1)
decoder_rnn(const float* __restrict__ ctx,   // [64][512]
            const float* __restrict__ Wih0,  // [1536][513] (row stride 513!)
            const float* __restrict__ Whh0,
            const float* __restrict__ bih0,
            const float* __restrict__ bhh0g,
            const float* __restrict__ Wih1,
            const float* __restrict__ Whh1,
            const float* __restrict__ bih1g,
            const float* __restrict__ bhh1g,
            const float* __restrict__ Wo1,
            const float* __restrict__ bo1g,
            const float* __restrict__ Wo2,
            const float* __restrict__ bo2g,
            float* __restrict__ out,         // [64*1024 y][65536 h_i]
            float* __restrict__ ws)
{
  extern __shared__ char smem_raw[];
  SmemR0& S0 = *reinterpret_cast<SmemR0*>(smem_raw);
  SmemR2& S2 = *reinterpret_cast<SmemR2*>(smem_raw);
  SmemR3& S3 = *reinterpret_cast<SmemR3*>(smem_raw);
  const int tid = threadIdx.x;
  const int wg  = blockIdx.x;

  ushort* hp  = (ushort*)ws;                 // h0hi[2]@0/32768, h0lo[2]@65536/
                                             // 98304, h1hi@131072, h1lo@163840
  float* yout = (float*)ws + 196608;         // 2 x 2048
  int*  ibase = (int*)((float*)ws + 200704);
  int* gslots = ibase;                       // [256] gbar
  int* epoch  = ibase + 256;
  int* mbox   = ibase + 512;                 // 256 lines x 32 ints
                                             // slots: [0]=h0, [1]=h1a/y,
                                             //        [2]=h1b

  const float bo2v = bo2g[0];

  // ---------------- init (swaps -> LLC; once, off critical path) ----------
  for (int i = wg*NT + tid; i < 200704; i += NWG*NT)
    SWP((uint*)ws + i, 0u);
  if (wg == 0)
    for (int i = tid; i < 256*32; i += NT) SWP(mbox + i, 0);

  const int gid   = wg >> 7;                 // 2 independent 32-batch machines
  const int m     = wg & 127;
  const int bbase = 32*gid;
  int role, j, bh = 0;
  if (m < 32){ role = 0; j = m; }
  else if (m < 96){ role = 2; bh = (m - 32) >> 5; j = m & 31; }
  else { role = 3; j = m - 96; }

  if (role == 0){
    for (int i = tid; i < 48*512; i += NT){
      int r = i >> 9, k = i & 511;
      int g3 = r >> 4, n = r & 15;
      float wv = Whh0[(size_t)(g3*512 + 16*j + n)*512 + k];
      ushort hh = bfrnd(wv);
      S0.wpl[0][r*520 + k] = hh;
      S0.wpl[1][r*520 + k] = bfrnd(wv - bf2f(hh));
    }
    if (tid < 48){
      int g3 = tid >> 4, n = tid & 15;
      S0.wcol[g3][n] = Wih0[(size_t)(g3*512 + 16*j + n)*513 + 512];
    }
    if (tid < 16) S0.bhnN[tid] = bhh0g[2*512 + 16*j + tid];
    for (int idx = tid; idx < 1536; idx += NT){   // 48 rows x 32 local b
      int r = idx >> 5, bl = idx & 31;
      int g3 = r >> 4, n = r & 15;
      int grow = g3*512 + 16*j + n;
      const float* wr = Wih0 + (size_t)grow*513;
      const float* cx = ctx  + (size_t)(bbase + bl)*512;
      float s = bih0[grow];
      if (g3 < 2) s += bhh0g[grow];
      #pragma unroll 4
      for (int k = 0; k < 512; ++k) s += wr[k]*cx[k];
      S0.gictx[g3*1088 + n*68 + bl] = s;
    }
  } else if (role == 2){
    for (int i = tid; i < 48*512; i += NT){
      int r = i >> 9, k = i & 511;
      int g3 = r >> 4, n = r & 15;
      size_t row = (size_t)(g3*512 + 16*j + n)*512 + k;
      float wv = Whh1[row];
      ushort hh = bfrnd(wv);
      S2.whh[0][r*520 + k] = hh;
      S2.whh[1][r*520 + k] = bfrnd(wv - bf2f(hh));
      S2.wih[r*520 + k] = bfrnd(Wih1[row]);       // HI ONLY
    }
    if (tid < 16){
      int n = tid;
      S2.bsumR[n] = bih1g[16*j + n]       + bhh1g[16*j + n];
      S2.bsumZ[n] = bih1g[512 + 16*j + n] + bhh1g[512 + 16*j + n];
      S2.binN[n]  = bih1g[1024 + 16*j + n];
      S2.bhnN[n]  = bhh1g[1024 + 16*j + n];
    }
  } else {
    for (int i = tid; i < 16*512; i += NT){
      int r = i >> 9, k = i & 511;
      float wv = Wo1[(size_t)(16*j + r)*512 + k];
      ushort hh = bfrnd(wv);
      S3.wpl[0][r*520 + k] = hh;
      S3.wpl[1][r*520 + k] = bfrnd(wv - bf2f(hh));
    }
    if (tid < 16){ S3.bo1v[tid] = bo1g[16*j + tid]; S3.wo2v[tid] = Wo2[16*j + tid]; }
  }

  gbar(gslots, epoch, wg, tid, 1);

  int* myline = mbox + wg*32;
  const int gb = gid*128;

  const int v   = tid >> 6;
  const int l   = tid & 63;
  const int q   = l >> 4;
  const int col = l & 15;
  const int ng  = 16*j + col;

  if (role == 0){
    const int bblk  = v & 1;
    const int aoffB = (bbase + 16*bblk + col)*512 + q*8;
    const int b0wL  = 16*bblk + 4*q;
    float hc0 = 0.f, hc1 = 0.f, hc2 = 0.f, hc3 = 0.f;
    for (int t = 0; t < TT; ++t){
      const int r0 = t & 1, w0 = r0 ^ 1;
      waitmail(myline + 0, 32*t, tid);       // h0[t-1] complete
      const ushort* rH = hp + r0*32768;
      const ushort* rL = hp + 65536 + r0*32768;
      ushort*       wH = hp + w0*32768;
      ushort*       wL = hp + 65536 + w0*32768;
      f32x4 acc0={0,0,0,0}, acc1={0,0,0,0}, acc2={0,0,0,0};
      if (v < 2){
        DECL_HILO(rH, rL)
        RUN16(MS3F)
      }
      waitmail(myline + 1, 32*t, tid);       // y[t-1] partials at LLC
      if (tid < 32){
        float s = 0.f;
        if (t > 0){
          const float* yp = yout + ((t-1)&1)*2048 + bbase + tid;
          float vv[32];
          #pragma unroll
          for (int jj = 0; jj < 32; ++jj)
            LD1SCD(vv[jj], yp + jj*64)
          VMBAR8(vv[0],vv[1],vv[2],vv[3],vv[4],vv[5],vv[6],vv[7])
          VMBAR8(vv[8],vv[9],vv[10],vv[11],vv[12],vv[13],vv[14],vv[15])
          VMBAR8(vv[16],vv[17],vv[18],vv[19],vv[20],vv[21],vv[22],vv[23])
          VMBAR8(vv[24],vv[25],vv[26],vv[27],vv[28],vv[29],vv[30],vv[31])
          #pragma unroll
          for (int jj = 0; jj < 32; ++jj) s += vv[jj];
        }
        float pv = fmaxf(s + bo2v, 0.f);
        S0.prevS[tid] = pv;
        if (j == 0 && t > 0) out[(size_t)(bbase + tid)*TT + (t-1)] = pv;
      }
      __syncthreads();
      if (v < 2){
        f32x4 pv4 = *(const f32x4*)&S0.prevS[b0wL];
        f32x4 gR = *(const f32x4*)&S0.gictx[0*1088 + col*68 + b0wL];
        f32x4 gZ = *(const f32x4*)&S0.gictx[1*1088 + col*68 + b0wL];
        f32x4 gN = *(const f32x4*)&S0.gictx[2*1088 + col*68 + b0wL];
        float wc0 = S0.wcol[0][col], wc1 = S0.wcol[1][col], wc2 = S0.wcol[2][col];
        float bhn = S0.bhnN[col];
        #define E0(i, HC) { \
          float rr = sigm(gR[i] + pv4[i]*wc0 + acc0[i]); \
          float zz = sigm(gZ[i] + pv4[i]*wc1 + acc1[i]); \
          float nn = tanh_f(gN[i] + pv4[i]*wc2 + rr*(acc2[i] + bhn)); \
          float h = (1.f-zz)*nn + zz*HC; \
          HC = h; \
          ushort hh_ = bfrnd(h); \
          uint hu_ = hh_, lu_ = bfrnd(h - bf2f(hh_)); \
          STSH(wH + (size_t)(bbase + b0wL + (i))*512 + ng, hu_) \
          STSH(wL + (size_t)(bbase + b0wL + (i))*512 + ng, lu_) }
        E0(0,hc0) E0(1,hc1) E0(2,hc2) E0(3,hc3)
        #undef E0
      }
      drain_sync();
      if (tid < 96)                          // role0 lines 0..31 + role2 32..95
        FADDI(mbox + (gb + tid)*32 + 0);
    }
  } else if (role == 2){
    ushort* p1H = hp + 131072;
    ushort* p1L = hp + 163840;
    const int bb16  = bbase + 16*bh;
    const int kq    = v*128;                 // k-quarter per wave
    const int aoffA = (bb16 + col)*512 + kq + q*8;
    float hc0 = 0.f, hc1 = 0.f, hc2 = 0.f, hc3 = 0.f;   // wave0: batches 4q+i
    for (int t = 0; t < TT; ++t){
      const int w0 = (t & 1) ^ 1;
      // -------- phase A (slack-funded): gh1 = Whh1 @ h1[t-1], full prec ----
      waitmail(myline + 1 + bh, 32*t, tid);  // own-half h1[t-1] rows complete
      f32x4 aR={0,0,0,0}, aZ={0,0,0,0}, aNi={0,0,0,0}, aNh={0,0,0,0};
      {
        uint4v ha0,ha1,ha2,ha3, la0,la1,la2,la3;
        LD4A(ha0, p1H, aoffA+0*32) LD4A(ha1, p1H, aoffA+1*32)
        LD4A(ha2, p1H, aoffA+2*32) LD4A(ha3, p1H, aoffA+3*32)
        LD4A(la0, p1L, aoffA+0*32) LD4A(la1, p1L, aoffA+1*32)
        LD4A(la2, p1L, aoffA+2*32) LD4A(la3, p1L, aoffA+3*32)
        VMBAR8(ha0,ha1,ha2,ha3,la0,la1,la2,la3)
        RUN4(GH1)
      }
      // -------- phase B (critical): gi = Wih1_hi @ h0hi[t] ----------------
      waitmail(myline + 0, 32*(t+1), tid);   // h0[t] complete
      {
        const ushort* rH = hp + w0*32768;
        uint4v ga0,ga1,ga2,ga3;
        LD4A(ga0, rH, aoffA+0*32) LD4A(ga1, rH, aoffA+1*32)
        LD4A(ga2, rH, aoffA+2*32) LD4A(ga3, rH, aoffA+3*32)
        VMBAR4(ga0,ga1,ga2,ga3)
        RUN4(GI1)
      }
      // -------- combine k-quarters, EW, store -----------------------------
      if (v >= 1){
        *(f32x4*)&S2.xk[v-1][l][0]  = aR;
        *(f32x4*)&S2.xk[v-1][l][4]  = aZ;
        *(f32x4*)&S2.xk[v-1][l][8]  = aNi;
        *(f32x4*)&S2.xk[v-1][l][12] = aNh;
      }
      __syncthreads();
      if (v == 0){
        #pragma unroll
        for (int w = 0; w < 3; ++w){
          aR  += *(const f32x4*)&S2.xk[w][l][0];
          aZ  += *(const f32x4*)&S2.xk[w][l][4];
          aNi += *(const f32x4*)&S2.xk[w][l][8];
          aNh += *(const f32x4*)&S2.xk[w][l][12];
        }
        float bsR = S2.bsumR[col], bsZ = S2.bsumZ[col];
        float biN = S2.binN[col],  bhN = S2.bhnN[col];
        #define E1(i, HC) { \
          float r1 = sigm(aR[i] + bsR); \
          float z1 = sigm(aZ[i] + bsZ); \
          float n1 = tanh_f(aNi[i] + biN + r1*(aNh[i] + bhN)); \
          float h = (1.f-z1)*n1 + z1*HC; \
          HC = h; \
          ushort hh_ = bfrnd(h); \
          uint hu_ = hh_, lu_ = bfrnd(h - bf2f(hh_)); \
          STSH(p1H + (size_t)(bb16 + 4*q + (i))*512 + ng, hu_) \
          STSH(p1L + (size_t)(bb16 + 4*q + (i))*512 + ng, lu_) }
        E1(0,hc0) E1(1,hc1) E1(2,hc2) E1(3,hc3)
        #undef E1
      }
      drain_sync();
      if (tid < 96)                          // role2 lines 32..95 + role3 96..127
        FADDI(mbox + (gb + 32 + tid)*32 + 1 + bh);
    }
  } else {
    const ushort* rH = hp + 131072;          // h1 hi plane ONLY (critical)
    const int bblk  = v & 1;
    const int kb    = (v >> 1)*256;
    const int aoff8 = (bbase + 16*bblk + col)*512 + kb + q*8;
    const int b0wL  = 16*bblk + 4*q;
    for (int t = 0; t < TT; ++t){
      waitmail2(myline + 1, myline + 2, 32*(t+1), tid);  // h1[t] both halves
      f32x4 acc0={0,0,0,0};
      {
        DECL_HI8(rH)
        RUN8(MS1H)
      }
      if (v >= 2)
        *(f32x4*)&S3.xk[bblk][l][0] = acc0;
      __syncthreads();
      if (v < 2){
        acc0 += *(const f32x4*)&S3.xk[bblk][l][0];
        float s0 = S3.wo2v[col]*fmaxf(acc0[0] + S3.bo1v[col], 0.f);
        float s1 = S3.wo2v[col]*fmaxf(acc0[1] + S3.bo1v[col], 0.f);
        float s2 = S3.wo2v[col]*fmaxf(acc0[2] + S3.bo1v[col], 0.f);
        float s3 = S3.wo2v[col]*fmaxf(acc0[3] + S3.bo1v[col], 0.f);
        #pragma unroll
        for (int d = 1; d < 16; d <<= 1){
          s0 += __shfl_xor(s0, d);
          s1 += __shfl_xor(s1, d);
          s2 += __shfl_xor(s2, d);
          s3 += __shfl_xor(s3, d);
        }
        if (col == 0){
          float* rp = yout + (t&1)*2048 + j*64 + bbase + b0wL;
          f32x4 sv = {s0, s1, s2, s3};
          ST4SC(rp, sv)
        }
      }
      drain_sync();
      if (tid < 32)                          // role0 lines, y slot
        FADDI(mbox + (gb + tid)*32 + 1);
    }
  }

  // ---------------- finale: one global release/acquire barrier ------------
  gbar(gslots, epoch, wg, tid, 2);
  if (wg == 0 && tid < 64){
    float s = 0.f;
    const float* yp = yout + 2048 + tid;     // parity of t=1023 is 1
    #pragma unroll
    for (int jj = 0; jj < 32; ++jj) s += ALDF(yp + jj*64);
    out[(size_t)tid*TT + 1023] = fmaxf(s + bo2v, 0.f);
  }
  {
    int g = wg*256 + tid;                    // 256 WGs x 256 thr = 65536
    if (g < 32768) out[65536 + g] = bf2f(hp[g]) + bf2f(hp[65536 + g]);
    else {
      int g2 = g - 32768;
      out[65536 + g] = bf2f(hp[131072 + g2]) + bf2f(hp[163840 + g2]);
    }
  }
}

extern "C" void kernel_launch(void* const* d_in, const int* in_sizes, int n_in,
                              void* d_out, int out_size, void* d_ws, size_t ws_size,
                              hipStream_t stream){
  const float* ctx   = (const float*)d_in[0];
  const float* Wih0  = (const float*)d_in[2];
  const float* Whh0  = (const float*)d_in[3];
  const float* bih0  = (const float*)d_in[4];
  const float* bhh0  = (const float*)d_in[5];
  const float* Wih1  = (const float*)d_in[6];
  const float* Whh1  = (const float*)d_in[7];
  const float* bih1  = (const float*)d_in[8];
  const float* bhh1  = (const float*)d_in[9];
  const float* Wo1   = (const float*)d_in[10];
  const float* bo1   = (const float*)d_in[11];
  const float* Wo2   = (const float*)d_in[12];
  const float* bo2   = (const float*)d_in[13];

  (void)in_sizes; (void)n_in; (void)out_size; (void)ws_size;

  const int smem_sz = (int)sizeof(SmemR2);   // largest overlay (162,304 B)
  (void)hipFuncSetAttribute((const void*)decoder_rnn,
                            hipFuncAttributeMaxDynamicSharedMemorySize,
                            smem_sz);

  decoder_rnn<<<NWG, NT, smem_sz, stream>>>(
      ctx, Wih0, Whh0, bih0, bhh0, Wih1, Whh1, bih1, bhh1,
      Wo1, bo1, Wo2, bo2, (float*)d_out, (float*)d_ws);
}